// Round 3
// baseline (165.374 us; speedup 1.0000x reference)
//
#include <hip/hip_runtime.h>
#include <hip/hip_cooperative_groups.h>

namespace cg = cooperative_groups;

// y[32,8192] = x[32,8192] @ (A[8192,64] @ B[64,8192])^T + bias
// Factored: t = x @ B^T [32,64]; y = t @ A^T + bias.
// Single cooperative kernel: phase 1 (blocks 0..127) writes split-K partials of t
// to d_ws; grid.sync(); phase 2 (all 256 blocks) reduces and applies A^T + bias.
// A-tile is prefetched into registers before the barrier to overlap phase-1 latency.

#define BATCH 32
#define RANK  64
#define OUTF  8192
#define KCH   128            // phase-1 chunks; chunk = 64 floats = 16 float4

__global__ __launch_bounds__(256) void lr_fused(const float* __restrict__ x,
                                                const float* __restrict__ A,
                                                const float* __restrict__ B,
                                                const float* __restrict__ bias,
                                                float* __restrict__ part,
                                                float* __restrict__ y) {
    const int bid = blockIdx.x;
    const int tid = threadIdx.x;

    __shared__ float4 as[256 * 16];   // 64 KB A tile (swizzled)
    __shared__ float4 xs[BATCH * 16]; //  8 KB
    __shared__ float4 bs[RANK * 16];  // 16 KB
    __shared__ float  ts[4 * RANK];   //  1 KB reduced t rows
    // 89 KB total -> 1 block/CU -> 256 blocks co-resident on 256 CUs.

    const int og = bid >> 3;          // 0..31  : output group of 256
    const int b0 = (bid & 7) * 4;     // 0..28  : batch group of 4

    // ---- 1) Prefetch this block's A tile into registers (coalesced) ----
    const float4* A4 = (const float4*)A;       // A[o][r] -> A4[o*16 + r4]
    float4 areg[16];
#pragma unroll
    for (int it = 0; it < 16; ++it)
        areg[it] = A4[og * 4096 + tid + it * 256];  // rows og*256..+255, fully coalesced

    // ---- 2) Phase 1: part[c][32][64] = x[:,chunk_c] @ B[:,chunk_c]^T ----
    if (bid < KCH) {
        const int c = bid;
        const float4* x4 = (const float4*)x;   // row stride 2048 f4
        const float4* b4 = (const float4*)B;
#pragma unroll
        for (int it = 0; it < 2; ++it) {
            int gi = tid + it * 256, row = gi >> 4, kk = gi & 15;
            xs[row * 16 + (kk ^ (row & 15))] = x4[row * 2048 + c * 16 + kk];
        }
#pragma unroll
        for (int it = 0; it < 4; ++it) {
            int gi = tid + it * 256, row = gi >> 4, kk = gi & 15;
            bs[row * 16 + (kk ^ (row & 15))] = b4[row * 2048 + c * 16 + kk];
        }
        __syncthreads();

        const int bq = tid >> 4;     // b rows: bq*2, bq*2+1
        const int rr = tid & 15;     // r cols: rr + 16j
        float acc[2][4] = {};
#pragma unroll
        for (int kk = 0; kk < 16; ++kk) {
            float4 xa[2], bb[4];
#pragma unroll
            for (int i = 0; i < 2; ++i) {
                int row = bq * 2 + i;
                xa[i] = xs[row * 16 + (kk ^ (row & 15))];
            }
#pragma unroll
            for (int j = 0; j < 4; ++j) {
                int r = rr + 16 * j;
                bb[j] = bs[r * 16 + (kk ^ (r & 15))];
            }
#pragma unroll
            for (int i = 0; i < 2; ++i)
#pragma unroll
                for (int j = 0; j < 4; ++j)
                    acc[i][j] += xa[i].x * bb[j].x + xa[i].y * bb[j].y +
                                 xa[i].z * bb[j].z + xa[i].w * bb[j].w;
        }
#pragma unroll
        for (int i = 0; i < 2; ++i)
#pragma unroll
            for (int j = 0; j < 4; ++j)
                part[c * 2048 + (bq * 2 + i) * 64 + 16 * j + rr] = acc[i][j];
    }

    // ---- 3) Spill A tile regs -> LDS (independent of phase 1) ----
#pragma unroll
    for (int it = 0; it < 16; ++it) {
        int gi = tid + it * 256, ol = gi >> 4, r4 = gi & 15;
        as[ol * 16 + (r4 ^ (ol & 15))] = areg[it];
    }

    // ---- 4) Grid barrier (cross-XCD visibility of part[]) ----
    __threadfence();
    cg::this_grid().sync();
    __threadfence();

    // ---- 5) Reduce partials for this block's 4x64 t slice ----
    float s = 0.f;
#pragma unroll 16
    for (int c = 0; c < KCH; ++c) s += part[c * 2048 + b0 * 64 + tid];
    ts[tid] = s;
    __syncthreads();

    // ---- 6) y = t @ A^T + bias ----
    const int o = og * 256 + tid;
    const float bv = bias[o];
    float accv[4] = {bv, bv, bv, bv};
    const float4* t4 = (const float4*)ts;
#pragma unroll
    for (int r4 = 0; r4 < 16; ++r4) {
        float4 a = as[tid * 16 + (r4 ^ (tid & 15))];  // 2-way per 16-lane phase: free
#pragma unroll
        for (int jb = 0; jb < 4; ++jb) {
            float4 tv = t4[jb * 16 + r4];             // wave-uniform broadcast
            accv[jb] += a.x * tv.x + a.y * tv.y + a.z * tv.z + a.w * tv.w;
        }
    }
#pragma unroll
    for (int jb = 0; jb < 4; ++jb)
        y[(b0 + jb) * OUTF + o] = accv[jb];           // coalesced
}

extern "C" void kernel_launch(void* const* d_in, const int* in_sizes, int n_in,
                              void* d_out, int out_size, void* d_ws, size_t ws_size,
                              hipStream_t stream) {
    const float* x    = (const float*)d_in[0];   // [32, 8192]
    const float* A    = (const float*)d_in[1];   // [8192, 64]
    const float* B    = (const float*)d_in[2];   // [64, 8192]
    const float* bias = (const float*)d_in[3];   // [8192]
    float*       y    = (float*)d_out;           // [32, 8192]
    float*       part = (float*)d_ws;            // [128][32][64] partials (1 MB)

    void* args[] = {(void*)&x, (void*)&A, (void*)&B, (void*)&bias, (void*)&part, (void*)&y};
    hipLaunchCooperativeKernel((void*)lr_fused, dim3(256), dim3(256), args, 0, stream);
}

// Round 4
// 104.910 us; speedup vs baseline: 1.5763x; 1.5763x over previous
//
#include <hip/hip_runtime.h>

// y[32,8192] = x[32,8192] @ (A[8192,64] @ B[64,8192])^T + bias
// Factored: t = x @ B^T [32,64]; y = t @ A^T + bias.
// Single kernel, custom device-scope arrive/spin barrier (NOT cg::grid.sync —
// measured 85 us of stall in round 3). All 256 blocks co-resident by
// construction: 49 KB LDS -> >=3 blocks/CU capacity, grid == CU count.
//   phase 1: blocks 0..63 produce split-K partials part[64][32][64] (512 KB ws)
//   barrier: release fetch_add + acquire spin on flag (zeroed via 4B memset)
//   phase 2: every block reduces its 4x64 t-slice and applies A^T + bias.

#define BATCH 32
#define RANK  64
#define OUTF  8192
#define KCH   64          // producer blocks; chunk = 8192/64 = 128 floats = 32 f4
#define NBLK  256
#define PART_BYTES (KCH * BATCH * RANK * 4)   // 512 KB

__global__ __launch_bounds__(256) void lr_fused(const float* __restrict__ x,
                                                const float* __restrict__ A,
                                                const float* __restrict__ B,
                                                const float* __restrict__ bias,
                                                float* __restrict__ part,
                                                unsigned int* __restrict__ flag,
                                                float* __restrict__ y) {
    const int bid = blockIdx.x;
    const int tid = threadIdx.x;

    __shared__ float4 xs[BATCH * 32];  // 16 KB, kk XOR-swizzled
    __shared__ float4 bs[RANK * 32];   // 32 KB
    __shared__ float  ts[4 * RANK];    //  1 KB reduced t rows

    const int og = bid >> 3;           // 0..31 : outputs og*256..+255
    const int b0 = (bid & 7) * 4;      // 0..28 : batches b0..b0+3
    const int o  = og * 256 + tid;

    // ---- Prefetch this thread's A row + bias (in flight during phase 1) ----
    const float4* A4 = (const float4*)A;    // A[o][r] -> A4[o*16 + r4]
    float4 areg[16];
#pragma unroll
    for (int r4 = 0; r4 < 16; ++r4) areg[r4] = A4[o * 16 + r4];
    const float bv = bias[o];

    // ---- Phase 1: part[c][32][64] = x[:,chunk_c] @ B[:,chunk_c]^T ----
    if (bid < KCH) {
        const int c = bid;
        const float4* x4 = (const float4*)x;   // row stride 2048 f4
        const float4* b4 = (const float4*)B;
#pragma unroll
        for (int it = 0; it < 4; ++it) {       // 1024 f4 of x-chunk
            int gi = tid + it * 256, row = gi >> 5, kk = gi & 31;
            xs[row * 32 + (kk ^ (row & 31))] = x4[row * 2048 + c * 32 + kk];
        }
#pragma unroll
        for (int it = 0; it < 8; ++it) {       // 2048 f4 of B-chunk
            int gi = tid + it * 256, row = gi >> 5, kk = gi & 31;
            bs[row * 32 + (kk ^ (row & 31))] = b4[row * 2048 + c * 32 + kk];
        }
        __syncthreads();

        const int bq = tid >> 4;   // b rows: bq*2, bq*2+1
        const int rr = tid & 15;   // r cols: rr + 16j
        float acc[2][4] = {};
#pragma unroll 8
        for (int kk = 0; kk < 32; ++kk) {
            float4 xa[2], bb[4];
#pragma unroll
            for (int i = 0; i < 2; ++i) {
                int row = bq * 2 + i;
                xa[i] = xs[row * 32 + (kk ^ (row & 31))];   // 4 rows/wave -> broadcast
            }
#pragma unroll
            for (int j = 0; j < 4; ++j) {
                int r = rr + 16 * j;
                bb[j] = bs[r * 32 + (kk ^ (r & 31))];       // 2-way -> free (m136)
            }
#pragma unroll
            for (int i = 0; i < 2; ++i)
#pragma unroll
                for (int j = 0; j < 4; ++j)
                    acc[i][j] += xa[i].x * bb[j].x + xa[i].y * bb[j].y +
                                 xa[i].z * bb[j].z + xa[i].w * bb[j].w;
        }
#pragma unroll
        for (int i = 0; i < 2; ++i)
#pragma unroll
            for (int j = 0; j < 4; ++j)
                part[c * 2048 + (bq * 2 + i) * 64 + 16 * j + rr] = acc[i][j];
    }

    // ---- Barrier: arrive (release) + spin (acquire), device scope ----
    __syncthreads();   // drains vmcnt: producer stores are in L2 before arrive
    if (tid == 0) {
        __threadfence();   // agent release: write back dirty L2 (part -> L3)
        __hip_atomic_fetch_add(flag, 1u, __ATOMIC_RELEASE, __HIP_MEMORY_SCOPE_AGENT);
        while (__hip_atomic_load(flag, __ATOMIC_ACQUIRE, __HIP_MEMORY_SCOPE_AGENT) < NBLK)
            __builtin_amdgcn_s_sleep(1);
        __threadfence();   // agent acquire: invalidate stale L1/L2 (poison lines)
    }
    __syncthreads();

    // ---- Phase 2a: reduce partials for this block's 4x64 t slice ----
    {
        float s = 0.f;
#pragma unroll 16
        for (int c = 0; c < KCH; ++c) s += part[c * 2048 + b0 * 64 + tid]; // 1KB/iter coalesced
        ts[tid] = s;
    }
    __syncthreads();

    // ---- Phase 2b: y = t @ A^T + bias ----
    float accv[4] = {bv, bv, bv, bv};
    const float4* t4 = (const float4*)ts;
#pragma unroll
    for (int r4 = 0; r4 < 16; ++r4) {
        float4 a = areg[r4];
#pragma unroll
        for (int jb = 0; jb < 4; ++jb) {
            float4 tv = t4[jb * 16 + r4];   // wave-uniform -> LDS broadcast, free
            accv[jb] += a.x * tv.x + a.y * tv.y + a.z * tv.z + a.w * tv.w;
        }
    }
#pragma unroll
    for (int jb = 0; jb < 4; ++jb)
        y[(b0 + jb) * OUTF + o] = accv[jb];   // coalesced
}

extern "C" void kernel_launch(void* const* d_in, const int* in_sizes, int n_in,
                              void* d_out, int out_size, void* d_ws, size_t ws_size,
                              hipStream_t stream) {
    const float* x    = (const float*)d_in[0];   // [32, 8192]
    const float* A    = (const float*)d_in[1];   // [8192, 64]
    const float* B    = (const float*)d_in[2];   // [64, 8192]
    const float* bias = (const float*)d_in[3];   // [8192]
    float*       y    = (float*)d_out;           // [32, 8192]
    float*       part = (float*)d_ws;            // [64][32][64] partials
    unsigned int* flag = (unsigned int*)((char*)d_ws + PART_BYTES);

    hipMemsetAsync(flag, 0, sizeof(unsigned int), stream);  // ws is 0xAA-poisoned
    lr_fused<<<NBLK, 256, 0, stream>>>(x, A, B, bias, part, flag, y);
}

// Round 6
// 91.583 us; speedup vs baseline: 1.8057x; 1.1455x over previous
//
#include <hip/hip_runtime.h>

// y[32,8192] = x[32,8192] @ (A[8192,64] @ B[64,8192])^T + bias
// Factored: t = x @ B^T [32,64]; y = t @ A^T + bias.
// Single kernel, custom counting barrier. Round-4 lesson: an AGENT-scope
// ACQUIRE load in the spin loop emits buffer_inv (L1/L2 invalidate) PER POLL
// -> 256 spinners continuously wiped every XCD's L2 (47.9 us, FETCH 10.2 MB).
// Fix: RELEASE fetch_add once, RELAXED polls, ONE acquire fence on exit
// (via __builtin_amdgcn_fence — __hip_atomic_thread_fence doesn't exist).
// All 256 blocks co-resident: 49 KB LDS, grid == CU count -> no deadlock.
//   phase 1: blocks 0..63 produce split-K partials part[64][32][64] (512 KB ws)
//   phase 2: every block reduces its 4x64 t-slice and applies A^T + bias.

#define BATCH 32
#define RANK  64
#define OUTF  8192
#define KCH   64          // producer blocks; chunk = 8192/64 = 128 floats = 32 f4
#define NBLK  256
#define PART_BYTES (KCH * BATCH * RANK * 4)   // 512 KB

__global__ __launch_bounds__(256) void lr_fused(const float* __restrict__ x,
                                                const float* __restrict__ A,
                                                const float* __restrict__ B,
                                                const float* __restrict__ bias,
                                                float* __restrict__ part,
                                                unsigned int* __restrict__ flag,
                                                float* __restrict__ y) {
    const int bid = blockIdx.x;
    const int tid = threadIdx.x;

    __shared__ float4 xs[BATCH * 32];  // 16 KB, kk XOR-swizzled
    __shared__ float4 bs[RANK * 32];   // 32 KB
    __shared__ float  ts[4 * RANK];    //  1 KB reduced t rows

    const int og = bid >> 3;           // 0..31 : outputs og*256..+255
    const int b0 = (bid & 7) * 4;      // 0..28 : batches b0..b0+3
    const int o  = og * 256 + tid;

    // ---- Prefetch this thread's A row + bias (in flight during phase 1) ----
    const float4* A4 = (const float4*)A;    // A[o][r] -> A4[o*16 + r4]
    float4 areg[16];
#pragma unroll
    for (int r4 = 0; r4 < 16; ++r4) areg[r4] = A4[o * 16 + r4];
    const float bv = bias[o];

    // ---- Phase 1: part[c][32][64] = x[:,chunk_c] @ B[:,chunk_c]^T ----
    if (bid < KCH) {
        const int c = bid;
        const float4* x4 = (const float4*)x;   // row stride 2048 f4
        const float4* b4 = (const float4*)B;
#pragma unroll
        for (int it = 0; it < 4; ++it) {       // 1024 f4 of x-chunk
            int gi = tid + it * 256, row = gi >> 5, kk = gi & 31;
            xs[row * 32 + (kk ^ (row & 31))] = x4[row * 2048 + c * 32 + kk];
        }
#pragma unroll
        for (int it = 0; it < 8; ++it) {       // 2048 f4 of B-chunk
            int gi = tid + it * 256, row = gi >> 5, kk = gi & 31;
            bs[row * 32 + (kk ^ (row & 31))] = b4[row * 2048 + c * 32 + kk];
        }
        __syncthreads();

        const int bq = tid >> 4;   // b rows: bq*2, bq*2+1
        const int rr = tid & 15;   // r cols: rr + 16j
        float acc[2][4] = {};
#pragma unroll 8
        for (int kk = 0; kk < 32; ++kk) {
            float4 xa[2], bb[4];
#pragma unroll
            for (int i = 0; i < 2; ++i) {
                int row = bq * 2 + i;
                xa[i] = xs[row * 32 + (kk ^ (row & 31))];   // 4 rows/wave -> broadcast
            }
#pragma unroll
            for (int j = 0; j < 4; ++j) {
                int r = rr + 16 * j;
                bb[j] = bs[r * 32 + (kk ^ (r & 31))];       // 2-way -> free (m136)
            }
#pragma unroll
            for (int i = 0; i < 2; ++i)
#pragma unroll
                for (int j = 0; j < 4; ++j)
                    acc[i][j] += xa[i].x * bb[j].x + xa[i].y * bb[j].y +
                                 xa[i].z * bb[j].z + xa[i].w * bb[j].w;
        }
#pragma unroll
        for (int i = 0; i < 2; ++i)
#pragma unroll
            for (int j = 0; j < 4; ++j)
                part[c * 2048 + (bq * 2 + i) * 64 + 16 * j + rr] = acc[i][j];
    }

    // ---- Barrier: one release RMW, relaxed polls, one acquire fence ----
    __syncthreads();   // all waves' part stores issued before arrive
    if (tid == 0) {
        // RELEASE: waits stores + writes back dirty L2 once, then bumps flag.
        __hip_atomic_fetch_add(flag, 1u, __ATOMIC_RELEASE, __HIP_MEMORY_SCOPE_AGENT);
        // RELAXED polls: plain loads, NO per-poll cache invalidate.
        while (__hip_atomic_load(flag, __ATOMIC_RELAXED, __HIP_MEMORY_SCOPE_AGENT) < NBLK)
            __builtin_amdgcn_s_sleep(2);
        // Single ACQUIRE: one cache invalidate so part[] reads see remote writes.
        __builtin_amdgcn_fence(__ATOMIC_ACQUIRE, "agent");
    }
    __syncthreads();

    // ---- Phase 2a: reduce partials for this block's 4x64 t slice ----
    {
        float s = 0.f;
#pragma unroll 16
        for (int c = 0; c < KCH; ++c) s += part[c * 2048 + b0 * 64 + tid]; // 1KB/iter coalesced
        ts[tid] = s;
    }
    __syncthreads();

    // ---- Phase 2b: y = t @ A^T + bias ----
    float accv[4] = {bv, bv, bv, bv};
    const float4* t4 = (const float4*)ts;
#pragma unroll
    for (int r4 = 0; r4 < 16; ++r4) {
        float4 a = areg[r4];
#pragma unroll
        for (int jb = 0; jb < 4; ++jb) {
            float4 tv = t4[jb * 16 + r4];   // wave-uniform -> LDS broadcast, free
            accv[jb] += a.x * tv.x + a.y * tv.y + a.z * tv.z + a.w * tv.w;
        }
    }
#pragma unroll
    for (int jb = 0; jb < 4; ++jb)
        y[(b0 + jb) * OUTF + o] = accv[jb];   // coalesced
}

extern "C" void kernel_launch(void* const* d_in, const int* in_sizes, int n_in,
                              void* d_out, int out_size, void* d_ws, size_t ws_size,
                              hipStream_t stream) {
    const float* x    = (const float*)d_in[0];   // [32, 8192]
    const float* A    = (const float*)d_in[1];   // [8192, 64]
    const float* B    = (const float*)d_in[2];   // [64, 8192]
    const float* bias = (const float*)d_in[3];   // [8192]
    float*       y    = (float*)d_out;           // [32, 8192]
    float*       part = (float*)d_ws;            // [64][32][64] partials
    unsigned int* flag = (unsigned int*)((char*)d_ws + PART_BYTES);

    (void)hipMemsetAsync(flag, 0, sizeof(unsigned int), stream);  // ws is 0xAA-poisoned
    lr_fused<<<NBLK, 256, 0, stream>>>(x, A, B, bias, part, flag, y);
}